// Round 16
// baseline (121.285 us; speedup 1.0000x reference)
//
#include <hip/hip_runtime.h>

// B=8, T=2048, C=1024, H=64 single-head causal attention, f32 in/out.
// Round 16: balanced + fused attn. 512 blocks (R10's heavy/light reversed
// pairing, 2 blocks/CU @ 80 KB LDS); split-K merge done by LAST-arriving
// half via device-scope atomic ticket (no combine kernel, no spin,
// deterministic canonical-order merge). Inner loop = R15 body.
// cnt[] zeroed by wcvt each call (stream-ordered -> graph-replay safe).

typedef __attribute__((ext_vector_type(4))) short sv4;
typedef __attribute__((ext_vector_type(8))) short sv8;
typedef __attribute__((ext_vector_type(4))) float f32x4;

#define NB   8
#define TSEQ 2048
#define CDIM 1024
#define HD   64
#define MROWS (NB * TSEQ)   // 16384

__device__ __forceinline__ short f2s(float f) {
  union { float f; unsigned u; } v; v.f = f;
  unsigned u = v.u;
  u += 0x7fffu + ((u >> 16) & 1u);
  return (short)(u >> 16);
}
__device__ __forceinline__ unsigned pk2(float lo, float hi) {
  return (unsigned)(unsigned short)f2s(lo) | ((unsigned)(unsigned short)f2s(hi) << 16);
}
__device__ __forceinline__ void glds16(const short* g, short* l) {
  __builtin_amdgcn_global_load_lds(
      (const __attribute__((address_space(1))) unsigned int*)g,
      (__attribute__((address_space(3))) unsigned int*)l, 16, 0, 0);
}

// ---------------- Kernel 0: W f32 -> bf16 images + zero merge counters ----
__global__ __launch_bounds__(256) void wcvt(
    const float* __restrict__ Wq, const float* __restrict__ Wk,
    const float* __restrict__ Wv, short* __restrict__ wb,
    unsigned* __restrict__ cnt)
{
  if (blockIdx.x == 0) cnt[threadIdx.x] = 0;   // 256 counters
  int i = blockIdx.x * 256 + threadIdx.x;   // 0..24575
  int t = i / 3072;                         // 8 chunks x 3072 sv8
  int rem = i - t * 3072;
  int r = rem >> 4, s = rem & 15;
  int j = r >> 6, wrow = r & 63;
  const float* W = (j == 0) ? Wq : (j == 1) ? Wk : Wv;
  const float* src = W + (size_t)wrow * CDIM + t * 128 + ((s ^ (wrow & 7)) << 3);
  float4 a = *(const float4*)src;
  float4 b = *(const float4*)(src + 4);
  sv8 v = {f2s(a.x), f2s(a.y), f2s(a.z), f2s(a.w),
           f2s(b.x), f2s(b.y), f2s(b.z), f2s(b.w)};
  *(sv8*)(wb + (size_t)i * 8) = v;
}

// ---------------- Kernel 1: QKV projection (R14/R15 exact) ----------------
__global__ __launch_bounds__(1024) void qkv_proj(
    const float* __restrict__ x,
    const short* __restrict__ wb,
    short* __restrict__ qw,
    short* __restrict__ kw,
    short* __restrict__ vtw)
{
  __shared__ short wlds[2][24576];  // 96 KB
  __shared__ short xlds[2][8192];   // 32 KB
  const int tid  = threadIdx.x;
  const int wid  = tid >> 6;
  const int lane = tid & 63;
  const int g    = lane >> 4;
  const int c16  = lane & 15;
  const int rowg = wid >> 2;
  const int ph   = wid & 3;
  const int row0 = blockIdx.x * 64;

  const int xr = tid >> 4, xs = tid & 15;
  const float* xsrc = x + (size_t)(row0 + xr) * CDIM + xs * 8;
  const int xwo = xr * 128 + ((xs ^ (xr & 7)) << 3);

  const int arow = rowg * 16 + c16;
  const int x7   = arow & 7;
  int rWo[3], rW7[3];
  #pragma unroll
  for (int p6 = 0; p6 < 3; ++p6) {
    int p = ph * 3 + p6;
    int r = (p >> 2) * 64 + (p & 3) * 16 + c16;
    rWo[p6] = r * 128;
    rW7[p6] = r & 7;
  }

  f32x4 acc[3];
  #pragma unroll
  for (int p6 = 0; p6 < 3; ++p6) acc[p6] = (f32x4){0.f, 0.f, 0.f, 0.f};

  float4 px[2][2];

  #pragma unroll
  for (int k2 = 0; k2 < 3; ++k2)
    glds16(wb + (size_t)(tid + k2 * 1024) * 8, &wlds[0][(tid + k2 * 1024) * 8]);
  px[0][0] = *(const float4*)(xsrc);
  px[0][1] = *(const float4*)(xsrc + 4);
  px[1][0] = *(const float4*)(xsrc + 128);
  px[1][1] = *(const float4*)(xsrc + 132);
  asm volatile("s_waitcnt vmcnt(2)" ::: "memory");
  {
    float4 A = px[0][0], B = px[0][1];
    sv8 v = {f2s(A.x), f2s(A.y), f2s(A.z), f2s(A.w),
             f2s(B.x), f2s(B.y), f2s(B.z), f2s(B.w)};
    *(sv8*)&xlds[0][xwo] = v;
  }
  asm volatile("s_waitcnt lgkmcnt(0)" ::: "memory");
  __builtin_amdgcn_sched_barrier(0);
  __builtin_amdgcn_s_barrier();

  #pragma unroll
  for (int t = 0; t < 8; ++t) {
    const int buf = t & 1;
    if (t < 7) {
      #pragma unroll
      for (int k2 = 0; k2 < 3; ++k2)
        glds16(wb + (size_t)((t + 1) * 3072 + tid + k2 * 1024) * 8,
               &wlds[buf ^ 1][(tid + k2 * 1024) * 8]);
    }
    if (t < 6) {
      px[t & 1][0] = *(const float4*)(xsrc + (t + 2) * 128);
      px[t & 1][1] = *(const float4*)(xsrc + (t + 2) * 128 + 4);
    }
    if (t < 7) {
      float4 A = px[(t + 1) & 1][0], B = px[(t + 1) & 1][1];
      sv8 v = {f2s(A.x), f2s(A.y), f2s(A.z), f2s(A.w),
               f2s(B.x), f2s(B.y), f2s(B.z), f2s(B.w)};
      *(sv8*)&xlds[buf ^ 1][xwo] = v;
    }
    #pragma unroll
    for (int kk = 0; kk < 4; ++kk) {
      int kslot = kk * 4 + g;
      sv8 a = *(const sv8*)&xlds[buf][arow * 128 + ((kslot ^ x7) << 3)];
      #pragma unroll
      for (int p6 = 0; p6 < 3; ++p6) {
        sv8 bfr = *(const sv8*)&wlds[buf][rWo[p6] + ((kslot ^ rW7[p6]) << 3)];
        acc[p6] = __builtin_amdgcn_mfma_f32_16x16x32_bf16(a, bfr, acc[p6], 0, 0, 0);
      }
    }
    if (t < 7) {
      if (t < 6) asm volatile("s_waitcnt vmcnt(2) lgkmcnt(0)" ::: "memory");
      else       asm volatile("s_waitcnt vmcnt(0) lgkmcnt(0)" ::: "memory");
      __builtin_amdgcn_sched_barrier(0);
      __builtin_amdgcn_s_barrier();
    }
  }

  #pragma unroll
  for (int p6 = 0; p6 < 3; ++p6) {
    int p = ph * 3 + p6, j = p >> 2, n = p & 3;
    int cc  = (n << 4) + c16;
    int rr0 = row0 + rowg * 16 + (g << 2);
    if (j == 2) {
      int b = rr0 >> 11, ti = rr0 & (TSEQ - 1);
      int kt = ti >> 6, key = ti & 63;
      sv4 v = {f2s(acc[p6][0]), f2s(acc[p6][1]), f2s(acc[p6][2]), f2s(acc[p6][3])};
      *(sv4*)&vtw[(((size_t)b * 32 + kt) * 64 + cc) * 64 +
                  ((((key >> 3) ^ (cc & 7)) << 3) | (key & 7))] = v;
    } else {
      #pragma unroll
      for (int r = 0; r < 4; ++r) {
        int rr = rr0 + r;
        if (j == 0) {
          qw[(size_t)rr * HD + cc] = f2s(acc[p6][r] * 0.03125f);
        } else {
          kw[(size_t)rr * HD + ((((cc >> 3) ^ (rr & 7)) << 3) | (cc & 7))] =
              f2s(acc[p6][r]);
        }
      }
    }
  }
}

// ---------------- Kernel 2: flash attention, balanced + atomic-fused ------
// 512 blocks x 256 threads (4 waves). bid<256: h0 of qb=bid>>3; bid>=256:
// h1 of qb=31-jj (reversed -> CU pairs heavy+light). 80 KB LDS, 2 blocks/CU.
// Last-arriving half merges via atomic ticket and writes out.
__global__ __launch_bounds__(256) void attn(
    const short* __restrict__ qw,
    const short* __restrict__ kw,
    const short* __restrict__ vtw,
    float* __restrict__ Opart,
    float* __restrict__ mlws,
    unsigned* __restrict__ cnt,
    float* __restrict__ out)
{
  __shared__ short kbuf[2][8192];     // 32 KB
  __shared__ short vbuf[2][8192];     // 32 KB
  __shared__ short bridge[4][2048];   // 16 KB (full-width 4 KB/wave)
  __shared__ unsigned ordsh;

  const int tid  = threadIdx.x;
  const int wid  = tid >> 6;
  const int lane = tid & 63;
  const int g    = lane >> 4;
  const int c16  = lane & 15;

  const int bid   = blockIdx.x;
  const int h     = bid >> 8;
  const int sub_  = bid & 255;
  const int batch = sub_ & 7;
  const int jj    = sub_ >> 3;
  const int qb    = h ? (31 - jj) : jj;
  const int sub   = (qb << 3) | batch;
  const int q0    = qb << 6;
  const size_t base = (size_t)batch * TSEQ * HD;

  const int ntot = (qb >> 1) + 1;        // 128-key tiles
  const int th_  = (ntot + 1) >> 1;
  const int t0   = h ? th_ : 0;
  const int t1   = h ? ntot : th_;

  const int qrow = q0 + (wid << 4) + c16;
  sv8 qa0 = *(const sv8*)(qw + base + (size_t)qrow * HD + (g << 3));
  sv8 qa1 = *(const sv8*)(qw + base + (size_t)qrow * HD + 32 + (g << 3));

  float m = -1e30f, l = 0.f;
  f32x4 o[4];
  #pragma unroll
  for (int n = 0; n < 4; ++n) o[n] = (f32x4){0.f, 0.f, 0.f, 0.f};

  short* br = &bridge[wid][0];
  const int sx = c16 & 15;

  #define STAGE(tt, bb)                                                      \
    {                                                                        \
      const short* ksrc = kw + base + (size_t)(tt) * 8192;                   \
      const short* vsrc = vtw + ((size_t)batch * 32 + (tt) * 2) * 4096;      \
      _Pragma("unroll")                                                      \
      for (int q = 0; q < 4; ++q)                                            \
        glds16(ksrc + (tid + q * 256) * 8, &kbuf[bb][(tid + q * 256) * 8]);  \
      _Pragma("unroll")                                                      \
      for (int q = 0; q < 4; ++q)                                            \
        glds16(vsrc + (tid + q * 256) * 8, &vbuf[bb][(tid + q * 256) * 8]);  \
    }

  if (t0 < t1) {
    STAGE(t0, 0);
    asm volatile("s_waitcnt vmcnt(0)" ::: "memory");
    __builtin_amdgcn_s_barrier();

    for (int t = t0; t < t1; ++t) {
      const int buf = (t - t0) & 1;
      if (t + 1 < t1) STAGE(t + 1, buf ^ 1);

      // ---- S^T = mfma(K, Q) ----
      f32x4 s[8];
      #pragma unroll
      for (int n = 0; n < 8; ++n) s[n] = (f32x4){0.f, 0.f, 0.f, 0.f};
      __builtin_amdgcn_s_setprio(1);
      #pragma unroll
      for (int n = 0; n < 8; ++n) {
        int kr = (n << 4) + c16;
        sv8 k0 = *(const sv8*)&kbuf[buf][kr * 64 + ((g ^ (kr & 7)) << 3)];
        s[n] = __builtin_amdgcn_mfma_f32_16x16x32_bf16(k0, qa0, s[n], 0, 0, 0);
        sv8 k1 = *(const sv8*)&kbuf[buf][kr * 64 + (((4 + g) ^ (kr & 7)) << 3)];
        s[n] = __builtin_amdgcn_mfma_f32_16x16x32_bf16(k1, qa1, s[n], 0, 0, 0);
      }
      __builtin_amdgcn_s_setprio(0);

      // ---- diagonal mask ----
      if (t == (qb >> 1)) {
        #pragma unroll
        for (int n = 0; n < 8; ++n) {
          int key = (t << 7) + (n << 4) + (g << 2);
          #pragma unroll
          for (int r = 0; r < 4; ++r)
            s[n][r] = (key + r <= qrow) ? s[n][r] : -1e30f;
        }
      }

      // ---- per-lane online softmax with defer-max (T13, THR=8) ----
      float pmax = -1e30f;
      #pragma unroll
      for (int n = 0; n < 8; ++n)
        pmax = fmaxf(pmax, fmaxf(fmaxf(s[n][0], s[n][1]), fmaxf(s[n][2], s[n][3])));
      float mnew  = m;
      float alpha = 1.f;
      const bool defer = (__all(pmax - m <= 8.0f) != 0);
      if (!defer) {
        float mx = fmaxf(pmax, __shfl_xor(pmax, 16));
        mx = fmaxf(mx, __shfl_xor(mx, 32));
        mnew  = fmaxf(m, mx);
        alpha = __expf(m - mnew);
        m = mnew;
      }

      float sum = 0.f;
      #pragma unroll
      for (int n = 0; n < 8; ++n) {
        float p0 = __expf(s[n][0] - mnew);
        float p1 = __expf(s[n][1] - mnew);
        float p2 = __expf(s[n][2] - mnew);
        float p3 = __expf(s[n][3] - mnew);
        sum += (p0 + p1) + (p2 + p3);
        int slot = 2 * n + (g >> 1);
        uint2 w2; w2.x = pk2(p0, p1); w2.y = pk2(p2, p3);
        *(uint2*)&br[c16 * 128 + ((slot ^ sx) << 3) + ((g & 1) << 2)] = w2;
      }
      sum += __shfl_xor(sum, 16);
      sum += __shfl_xor(sum, 32);

      if (!defer) {
        l = l * alpha + sum;
        float af[4];
        #pragma unroll
        for (int r = 0; r < 4; ++r) af[r] = __shfl(alpha, (g << 2) + r);
        #pragma unroll
        for (int n = 0; n < 4; ++n)
          #pragma unroll
          for (int r = 0; r < 4; ++r) o[n][r] *= af[r];
      } else {
        l += sum;
      }

      // ---- single fence, single PV cluster (128 keys) ----
      asm volatile("s_waitcnt lgkmcnt(0)" ::: "memory");
      __builtin_amdgcn_sched_barrier(0);
      __builtin_amdgcn_s_setprio(1);
      #pragma unroll
      for (int kk = 0; kk < 4; ++kk) {
        int kslot = (kk << 2) + g;
        sv8 pa = *(const sv8*)&br[c16 * 128 + ((kslot ^ sx) << 3)];
        #pragma unroll
        for (int n = 0; n < 4; ++n) {
          int vr = (n << 4) + c16;
          sv8 vf = *(const sv8*)&vbuf[buf][(kslot >> 3) * 4096 + vr * 64 +
                                           (((kslot & 7) ^ (vr & 7)) << 3)];
          o[n] = __builtin_amdgcn_mfma_f32_16x16x32_bf16(pa, vf, o[n], 0, 0, 0);
        }
      }
      __builtin_amdgcn_s_setprio(0);

      if (t + 1 < t1) {
        asm volatile("s_waitcnt vmcnt(0)" ::: "memory");
        __builtin_amdgcn_sched_barrier(0);
        __builtin_amdgcn_s_barrier();
      }
    }
  }

  // ---- publish partials ----
  float* myO = Opart + (size_t)(sub * 2 + h) * 4096;
  #pragma unroll
  for (int n = 0; n < 4; ++n) {
    #pragma unroll
    for (int r = 0; r < 4; ++r) {
      int row = (wid << 4) + (g << 2) + r;
      myO[row * 64 + (n << 4) + c16] = o[n][r];
    }
  }
  if (lane < 16) {
    int row = (wid << 4) + lane;
    mlws[((size_t)(sub * 2 + h) * 64 + row) * 2]     = m;
    mlws[((size_t)(sub * 2 + h) * 64 + row) * 2 + 1] = l;
  }

  // ---- atomic ticket: last-arriving half merges ----
  __threadfence();
  __syncthreads();
  if (tid == 0) ordsh = atomicAdd(&cnt[sub], 1u);
  __syncthreads();
  if (ordsh == 1u) {
    __threadfence();   // acquire other half's stores
    const int oh = h ^ 1;
    const float* oO  = Opart + (size_t)(sub * 2 + oh) * 4096;
    const float* oml = mlws + (size_t)(sub * 2 + oh) * 128;
    #pragma unroll
    for (int r = 0; r < 4; ++r) {
      int row = (wid << 4) + (g << 2) + r;
      float mm = __shfl(m, (g << 2) + r);
      float ll = __shfl(l, (g << 2) + r);
      float mo = oml[row * 2], lo = oml[row * 2 + 1];
      // canonical order: index 0 = h0, index 1 = h1 (deterministic)
      float m0 = (h == 0) ? mm : mo;
      float l0 = (h == 0) ? ll : lo;
      float m1 = (h == 0) ? mo : mm;
      float l1 = (h == 0) ? lo : ll;
      float M  = fmaxf(m0, m1);
      float a0 = __expf(m0 - M), a1 = __expf(m1 - M);
      float invL = 1.f / (l0 * a0 + l1 * a1);
      float amine = (h == 0) ? a0 : a1;
      float aoth  = (h == 0) ? a1 : a0;
      #pragma unroll
      for (int n = 0; n < 4; ++n) {
        float v = (o[n][r] * amine + oO[row * 64 + (n << 4) + c16] * aoth) * invL;
        out[base + (size_t)(q0 + row) * HD + (n << 4) + c16] = v;
      }
    }
  }
  #undef STAGE
}

extern "C" void kernel_launch(void* const* d_in, const int* in_sizes, int n_in,
                              void* d_out, int out_size, void* d_ws, size_t ws_size,
                              hipStream_t stream) {
  const float* x  = (const float*)d_in[0];
  const float* Wk = (const float*)d_in[1];
  const float* Wq = (const float*)d_in[2];
  const float* Wv = (const float*)d_in[3];
  float* out = (float*)d_out;

  short* qw  = (short*)d_ws;                        // 2 MB
  short* kw  = qw + (size_t)MROWS * HD;             // 2 MB (row-swizzled)
  short* vtw = kw + (size_t)MROWS * HD;             // 2 MB (tiled+swizzled)
  short* wb  = vtw + (size_t)NB * HD * TSEQ;        // 384 KB (pre-swizzled)
  float* Opart = (float*)(wb + (size_t)24576 * 8);  // 256*2*16KB = 8 MB
  float* mlws  = Opart + (size_t)512 * 4096;        // 256 KB
  unsigned* cnt = (unsigned*)(mlws + (size_t)512 * 128);  // 1 KB

  wcvt<<<dim3(96), dim3(256), 0, stream>>>(Wq, Wk, Wv, wb, cnt);
  qkv_proj<<<dim3(MROWS / 64), dim3(1024), 0, stream>>>(x, wb, qw, kw, vtw);
  attn<<<dim3(512), dim3(256), 0, stream>>>(qw, kw, vtw, Opart, mlws, cnt, out);
}

// Round 17
// 49.214 us; speedup vs baseline: 2.4644x; 2.4644x over previous
//
#include <hip/hip_runtime.h>

// B=8, T=2048, C=1024, H=64 single-head causal attention, f32 in/out.
// Round 17: REVERT to R15 exact (best measured: 49.03 us). R16's atomic-
// ticket fusion regressed 2.5x (device-scope threadfence + cross-XCD
// coherence cost >> imbalance savings). R15 = verified optimum.

typedef __attribute__((ext_vector_type(4))) short sv4;
typedef __attribute__((ext_vector_type(8))) short sv8;
typedef __attribute__((ext_vector_type(4))) float f32x4;

#define NB   8
#define TSEQ 2048
#define CDIM 1024
#define HD   64
#define MROWS (NB * TSEQ)   // 16384

__device__ __forceinline__ short f2s(float f) {
  union { float f; unsigned u; } v; v.f = f;
  unsigned u = v.u;
  u += 0x7fffu + ((u >> 16) & 1u);
  return (short)(u >> 16);
}
__device__ __forceinline__ unsigned pk2(float lo, float hi) {
  return (unsigned)(unsigned short)f2s(lo) | ((unsigned)(unsigned short)f2s(hi) << 16);
}
__device__ __forceinline__ void glds16(const short* g, short* l) {
  __builtin_amdgcn_global_load_lds(
      (const __attribute__((address_space(1))) unsigned int*)g,
      (__attribute__((address_space(3))) unsigned int*)l, 16, 0, 0);
}

// ---------------- Kernel 0: W f32 -> bf16, pre-swizzled 128-chunk images ----
__global__ __launch_bounds__(256) void wcvt(
    const float* __restrict__ Wq, const float* __restrict__ Wk,
    const float* __restrict__ Wv, short* __restrict__ wb)
{
  int i = blockIdx.x * 256 + threadIdx.x;   // 0..24575
  int t = i / 3072;                         // 8 chunks x 3072 sv8
  int rem = i - t * 3072;
  int r = rem >> 4, s = rem & 15;
  int j = r >> 6, wrow = r & 63;
  const float* W = (j == 0) ? Wq : (j == 1) ? Wk : Wv;
  const float* src = W + (size_t)wrow * CDIM + t * 128 + ((s ^ (wrow & 7)) << 3);
  float4 a = *(const float4*)src;
  float4 b = *(const float4*)(src + 4);
  sv8 v = {f2s(a.x), f2s(a.y), f2s(a.z), f2s(a.w),
           f2s(b.x), f2s(b.y), f2s(b.z), f2s(b.w)};
  *(sv8*)(wb + (size_t)i * 8) = v;
}

// ---------------- Kernel 1: QKV projection (R14 exact) ----------------
__global__ __launch_bounds__(1024) void qkv_proj(
    const float* __restrict__ x,
    const short* __restrict__ wb,
    short* __restrict__ qw,
    short* __restrict__ kw,
    short* __restrict__ vtw)
{
  __shared__ short wlds[2][24576];  // 96 KB
  __shared__ short xlds[2][8192];   // 32 KB
  const int tid  = threadIdx.x;
  const int wid  = tid >> 6;
  const int lane = tid & 63;
  const int g    = lane >> 4;
  const int c16  = lane & 15;
  const int rowg = wid >> 2;
  const int ph   = wid & 3;
  const int row0 = blockIdx.x * 64;

  const int xr = tid >> 4, xs = tid & 15;
  const float* xsrc = x + (size_t)(row0 + xr) * CDIM + xs * 8;
  const int xwo = xr * 128 + ((xs ^ (xr & 7)) << 3);

  const int arow = rowg * 16 + c16;
  const int x7   = arow & 7;
  int rWo[3], rW7[3];
  #pragma unroll
  for (int p6 = 0; p6 < 3; ++p6) {
    int p = ph * 3 + p6;
    int r = (p >> 2) * 64 + (p & 3) * 16 + c16;
    rWo[p6] = r * 128;
    rW7[p6] = r & 7;
  }

  f32x4 acc[3];
  #pragma unroll
  for (int p6 = 0; p6 < 3; ++p6) acc[p6] = (f32x4){0.f, 0.f, 0.f, 0.f};

  float4 px[2][2];

  #pragma unroll
  for (int k2 = 0; k2 < 3; ++k2)
    glds16(wb + (size_t)(tid + k2 * 1024) * 8, &wlds[0][(tid + k2 * 1024) * 8]);
  px[0][0] = *(const float4*)(xsrc);
  px[0][1] = *(const float4*)(xsrc + 4);
  px[1][0] = *(const float4*)(xsrc + 128);
  px[1][1] = *(const float4*)(xsrc + 132);
  asm volatile("s_waitcnt vmcnt(2)" ::: "memory");
  {
    float4 A = px[0][0], B = px[0][1];
    sv8 v = {f2s(A.x), f2s(A.y), f2s(A.z), f2s(A.w),
             f2s(B.x), f2s(B.y), f2s(B.z), f2s(B.w)};
    *(sv8*)&xlds[0][xwo] = v;
  }
  asm volatile("s_waitcnt lgkmcnt(0)" ::: "memory");
  __builtin_amdgcn_sched_barrier(0);
  __builtin_amdgcn_s_barrier();

  #pragma unroll
  for (int t = 0; t < 8; ++t) {
    const int buf = t & 1;
    if (t < 7) {
      #pragma unroll
      for (int k2 = 0; k2 < 3; ++k2)
        glds16(wb + (size_t)((t + 1) * 3072 + tid + k2 * 1024) * 8,
               &wlds[buf ^ 1][(tid + k2 * 1024) * 8]);
    }
    if (t < 6) {
      px[t & 1][0] = *(const float4*)(xsrc + (t + 2) * 128);
      px[t & 1][1] = *(const float4*)(xsrc + (t + 2) * 128 + 4);
    }
    if (t < 7) {
      float4 A = px[(t + 1) & 1][0], B = px[(t + 1) & 1][1];
      sv8 v = {f2s(A.x), f2s(A.y), f2s(A.z), f2s(A.w),
               f2s(B.x), f2s(B.y), f2s(B.z), f2s(B.w)};
      *(sv8*)&xlds[buf ^ 1][xwo] = v;
    }
    #pragma unroll
    for (int kk = 0; kk < 4; ++kk) {
      int kslot = kk * 4 + g;
      sv8 a = *(const sv8*)&xlds[buf][arow * 128 + ((kslot ^ x7) << 3)];
      #pragma unroll
      for (int p6 = 0; p6 < 3; ++p6) {
        sv8 bfr = *(const sv8*)&wlds[buf][rWo[p6] + ((kslot ^ rW7[p6]) << 3)];
        acc[p6] = __builtin_amdgcn_mfma_f32_16x16x32_bf16(a, bfr, acc[p6], 0, 0, 0);
      }
    }
    if (t < 7) {
      if (t < 6) asm volatile("s_waitcnt vmcnt(2) lgkmcnt(0)" ::: "memory");
      else       asm volatile("s_waitcnt vmcnt(0) lgkmcnt(0)" ::: "memory");
      __builtin_amdgcn_sched_barrier(0);
      __builtin_amdgcn_s_barrier();
    }
  }

  #pragma unroll
  for (int p6 = 0; p6 < 3; ++p6) {
    int p = ph * 3 + p6, j = p >> 2, n = p & 3;
    int cc  = (n << 4) + c16;
    int rr0 = row0 + rowg * 16 + (g << 2);
    if (j == 2) {
      int b = rr0 >> 11, ti = rr0 & (TSEQ - 1);
      int kt = ti >> 6, key = ti & 63;
      sv4 v = {f2s(acc[p6][0]), f2s(acc[p6][1]), f2s(acc[p6][2]), f2s(acc[p6][3])};
      *(sv4*)&vtw[(((size_t)b * 32 + kt) * 64 + cc) * 64 +
                  ((((key >> 3) ^ (cc & 7)) << 3) | (key & 7))] = v;
    } else {
      #pragma unroll
      for (int r = 0; r < 4; ++r) {
        int rr = rr0 + r;
        if (j == 0) {
          qw[(size_t)rr * HD + cc] = f2s(acc[p6][r] * 0.03125f);
        } else {
          kw[(size_t)rr * HD + ((((cc >> 3) ^ (rr & 7)) << 3) | (cc & 7))] =
              f2s(acc[p6][r]);
        }
      }
    }
  }
}

// ---------------- Kernel 2: fused flash attention + combine ----------------
// 256 blocks x 512 threads. Block = (batch, qb). Waves 0-3 = key-half 0,
// waves 4-7 = key-half 1; per-half K/V dbuf; uniform barrier count.
// Full-width 4 KB/wave bridge: one fence + one PV cluster per tile.
__global__ __launch_bounds__(512) void attn(
    const short* __restrict__ qw,
    const short* __restrict__ kw,
    const short* __restrict__ vtw,
    float* __restrict__ out)
{
  __shared__ short kbuf[2][2][8192];   // [half][dbuf] 64 KB
  __shared__ short vbuf[2][2][8192];   // 64 KB
  __shared__ short bridge[8][2048];    // 32 KB (4 KB/wave) -> total 160 KB

  const int tid  = threadIdx.x;
  const int wid  = tid >> 6;
  const int h    = wid >> 2;
  const int lwid = wid & 3;
  const int ltid = tid & 255;
  const int lane = tid & 63;
  const int g    = lane >> 4;
  const int c16  = lane & 15;

  const int bid   = blockIdx.x;
  const int batch = bid & 7;
  const int qb    = bid >> 3;           // 0..31
  const int q0    = qb << 6;
  const size_t base = (size_t)batch * TSEQ * HD;

  const int ntot = (qb >> 1) + 1;       // 128-key tiles
  const int th_  = (ntot + 1) >> 1;
  const int t0   = h ? th_ : 0;
  const int cnt  = h ? (ntot - th_) : th_;

  const int qrow = q0 + (lwid << 4) + c16;
  sv8 qa0 = *(const sv8*)(qw + base + (size_t)qrow * HD + (g << 3));
  sv8 qa1 = *(const sv8*)(qw + base + (size_t)qrow * HD + 32 + (g << 3));

  float m = -1e30f, l = 0.f;
  f32x4 o[4];
  #pragma unroll
  for (int n = 0; n < 4; ++n) o[n] = (f32x4){0.f, 0.f, 0.f, 0.f};

  short* br = &bridge[wid][0];
  const int sx = c16 & 15;

  #define STAGE(tt, bb)                                                        \
    {                                                                          \
      const short* ksrc = kw + base + (size_t)(tt) * 8192;                     \
      const short* vsrc = vtw + ((size_t)batch * 32 + (tt) * 2) * 4096;        \
      _Pragma("unroll")                                                        \
      for (int q = 0; q < 4; ++q)                                              \
        glds16(ksrc + (ltid + q * 256) * 8, &kbuf[h][bb][(ltid + q * 256) * 8]);\
      _Pragma("unroll")                                                        \
      for (int q = 0; q < 4; ++q)                                              \
        glds16(vsrc + (ltid + q * 256) * 8, &vbuf[h][bb][(ltid + q * 256) * 8]);\
    }

  if (cnt > 0) STAGE(t0, 0);
  asm volatile("s_waitcnt vmcnt(0)" ::: "memory");
  __builtin_amdgcn_s_barrier();

  for (int it = 0; it < th_; ++it) {
    const int t   = t0 + it;
    const int buf = it & 1;
    const bool valid = it < cnt;
    if (valid && (it + 1 < cnt)) STAGE(t + 1, buf ^ 1);

    if (valid) {
      // ---- S^T = mfma(K, Q): D[row=key 0..127, col=q] ----
      f32x4 s[8];
      #pragma unroll
      for (int n = 0; n < 8; ++n) s[n] = (f32x4){0.f, 0.f, 0.f, 0.f};
      __builtin_amdgcn_s_setprio(1);
      #pragma unroll
      for (int n = 0; n < 8; ++n) {
        int kr = (n << 4) + c16;
        sv8 k0 = *(const sv8*)&kbuf[h][buf][kr * 64 + ((g ^ (kr & 7)) << 3)];
        s[n] = __builtin_amdgcn_mfma_f32_16x16x32_bf16(k0, qa0, s[n], 0, 0, 0);
        sv8 k1 = *(const sv8*)&kbuf[h][buf][kr * 64 + (((4 + g) ^ (kr & 7)) << 3)];
        s[n] = __builtin_amdgcn_mfma_f32_16x16x32_bf16(k1, qa1, s[n], 0, 0, 0);
      }
      __builtin_amdgcn_s_setprio(0);

      // ---- diagonal mask ----
      if (t == (qb >> 1)) {
        #pragma unroll
        for (int n = 0; n < 8; ++n) {
          int key = (t << 7) + (n << 4) + (g << 2);
          #pragma unroll
          for (int r = 0; r < 4; ++r)
            s[n][r] = (key + r <= qrow) ? s[n][r] : -1e30f;
        }
      }

      // ---- per-lane online softmax with defer-max (T13, THR=8) ----
      float pmax = -1e30f;
      #pragma unroll
      for (int n = 0; n < 8; ++n)
        pmax = fmaxf(pmax, fmaxf(fmaxf(s[n][0], s[n][1]), fmaxf(s[n][2], s[n][3])));
      float mnew  = m;
      float alpha = 1.f;
      const bool defer = (__all(pmax - m <= 8.0f) != 0);
      if (!defer) {
        float mx = fmaxf(pmax, __shfl_xor(pmax, 16));
        mx = fmaxf(mx, __shfl_xor(mx, 32));
        mnew  = fmaxf(m, mx);
        alpha = __expf(m - mnew);
        m = mnew;
      }

      // exp + full-width bridge write (128 keys, one pass)
      float sum = 0.f;
      #pragma unroll
      for (int n = 0; n < 8; ++n) {
        float p0 = __expf(s[n][0] - mnew);
        float p1 = __expf(s[n][1] - mnew);
        float p2 = __expf(s[n][2] - mnew);
        float p3 = __expf(s[n][3] - mnew);
        sum += (p0 + p1) + (p2 + p3);
        int slot = 2 * n + (g >> 1);
        uint2 w2; w2.x = pk2(p0, p1); w2.y = pk2(p2, p3);
        *(uint2*)&br[c16 * 128 + ((slot ^ sx) << 3) + ((g & 1) << 2)] = w2;
      }
      sum += __shfl_xor(sum, 16);
      sum += __shfl_xor(sum, 32);

      if (!defer) {
        l = l * alpha + sum;
        float af[4];
        #pragma unroll
        for (int r = 0; r < 4; ++r) af[r] = __shfl(alpha, (g << 2) + r);
        #pragma unroll
        for (int n = 0; n < 4; ++n)
          #pragma unroll
          for (int r = 0; r < 4; ++r) o[n][r] *= af[r];
      } else {
        l += sum;
      }

      // ---- single fence, single PV cluster (128 keys) ----
      asm volatile("s_waitcnt lgkmcnt(0)" ::: "memory");
      __builtin_amdgcn_sched_barrier(0);
      __builtin_amdgcn_s_setprio(1);
      #pragma unroll
      for (int kk = 0; kk < 4; ++kk) {
        int kslot = (kk << 2) + g;
        sv8 pa = *(const sv8*)&br[c16 * 128 + ((kslot ^ sx) << 3)];
        #pragma unroll
        for (int n = 0; n < 4; ++n) {
          int vr = (n << 4) + c16;
          sv8 vf = *(const sv8*)&vbuf[h][buf][(kslot >> 3) * 4096 + vr * 64 +
                                             (((kslot & 7) ^ (vr & 7)) << 3)];
          o[n] = __builtin_amdgcn_mfma_f32_16x16x32_bf16(pa, vf, o[n], 0, 0, 0);
        }
      }
      __builtin_amdgcn_s_setprio(0);
    }

    // uniform end-of-iteration drain + barrier (ALL waves, both halves)
    asm volatile("s_waitcnt vmcnt(0)" ::: "memory");
    __builtin_amdgcn_sched_barrier(0);
    __builtin_amdgcn_s_barrier();
  }

  // ---- in-LDS merge: h1 publishes (O,m,l); h0 merges and writes out ----
  float* OLDS = (float*)&kbuf[0][0][0];   // 4096 floats (16 KB)
  float* mlds = OLDS + 4096;              // 64 floats
  float* llds = mlds + 64;                // 64 floats

  if (h == 1) {
    #pragma unroll
    for (int n = 0; n < 4; ++n) {
      #pragma unroll
      for (int r = 0; r < 4; ++r) {
        int row = (lwid << 4) + (g << 2) + r;
        OLDS[row * 64 + (n << 4) + c16] = o[n][r];
      }
    }
    if (lane < 16) {
      mlds[(lwid << 4) + lane] = m;
      llds[(lwid << 4) + lane] = l;
    }
  }
  __syncthreads();
  if (h == 0) {
    #pragma unroll
    for (int r = 0; r < 4; ++r) {
      int row = (lwid << 4) + (g << 2) + r;
      float m0 = __shfl(m, (g << 2) + r);
      float l0 = __shfl(l, (g << 2) + r);
      float m1 = mlds[row], l1 = llds[row];
      float M  = fmaxf(m0, m1);
      float a0 = __expf(m0 - M), a1 = __expf(m1 - M);
      float invL = 1.f / (l0 * a0 + l1 * a1);
      #pragma unroll
      for (int n = 0; n < 4; ++n) {
        float v = (o[n][r] * a0 + OLDS[row * 64 + (n << 4) + c16] * a1) * invL;
        out[base + (size_t)(q0 + row) * HD + (n << 4) + c16] = v;
      }
    }
  }
  #undef STAGE
}

extern "C" void kernel_launch(void* const* d_in, const int* in_sizes, int n_in,
                              void* d_out, int out_size, void* d_ws, size_t ws_size,
                              hipStream_t stream) {
  const float* x  = (const float*)d_in[0];
  const float* Wk = (const float*)d_in[1];
  const float* Wq = (const float*)d_in[2];
  const float* Wv = (const float*)d_in[3];
  float* out = (float*)d_out;

  short* qw  = (short*)d_ws;                        // 2 MB
  short* kw  = qw + (size_t)MROWS * HD;             // 2 MB (row-swizzled)
  short* vtw = kw + (size_t)MROWS * HD;             // 2 MB (tiled+swizzled)
  short* wb  = vtw + (size_t)NB * HD * TSEQ;        // 384 KB (pre-swizzled)

  wcvt<<<dim3(96), dim3(256), 0, stream>>>(Wq, Wk, Wv, wb);
  qkv_proj<<<dim3(MROWS / 64), dim3(1024), 0, stream>>>(x, wb, qw, kw, vtw);
  attn<<<dim3(256), dim3(512), 0, stream>>>(qw, kw, vtw, out);
}

// Round 19
// 49.181 us; speedup vs baseline: 2.4661x; 1.0007x over previous
//
#include <hip/hip_runtime.h>

// B=8, T=2048, C=1024, H=64 single-head causal attention, f32 in/out.
// Round 19: FINAL = R15 exact (best measured: 49.03 us, reproduced 3x).
// R18's KVBLK=256 is infeasible: dbuf'd K/V at 256 keys needs 256 KB LDS
// (>160); single-buffer variant gives back the R6->R7 prefetch win.
// All probed axes around this config are neutral-to-negative.

typedef __attribute__((ext_vector_type(4))) short sv4;
typedef __attribute__((ext_vector_type(8))) short sv8;
typedef __attribute__((ext_vector_type(4))) float f32x4;

#define NB   8
#define TSEQ 2048
#define CDIM 1024
#define HD   64
#define MROWS (NB * TSEQ)   // 16384

__device__ __forceinline__ short f2s(float f) {
  union { float f; unsigned u; } v; v.f = f;
  unsigned u = v.u;
  u += 0x7fffu + ((u >> 16) & 1u);
  return (short)(u >> 16);
}
__device__ __forceinline__ unsigned pk2(float lo, float hi) {
  return (unsigned)(unsigned short)f2s(lo) | ((unsigned)(unsigned short)f2s(hi) << 16);
}
__device__ __forceinline__ void glds16(const short* g, short* l) {
  __builtin_amdgcn_global_load_lds(
      (const __attribute__((address_space(1))) unsigned int*)g,
      (__attribute__((address_space(3))) unsigned int*)l, 16, 0, 0);
}

// ---------------- Kernel 0: W f32 -> bf16, pre-swizzled 128-chunk images ----
__global__ __launch_bounds__(256) void wcvt(
    const float* __restrict__ Wq, const float* __restrict__ Wk,
    const float* __restrict__ Wv, short* __restrict__ wb)
{
  int i = blockIdx.x * 256 + threadIdx.x;   // 0..24575
  int t = i / 3072;                         // 8 chunks x 3072 sv8
  int rem = i - t * 3072;
  int r = rem >> 4, s = rem & 15;
  int j = r >> 6, wrow = r & 63;
  const float* W = (j == 0) ? Wq : (j == 1) ? Wk : Wv;
  const float* src = W + (size_t)wrow * CDIM + t * 128 + ((s ^ (wrow & 7)) << 3);
  float4 a = *(const float4*)src;
  float4 b = *(const float4*)(src + 4);
  sv8 v = {f2s(a.x), f2s(a.y), f2s(a.z), f2s(a.w),
           f2s(b.x), f2s(b.y), f2s(b.z), f2s(b.w)};
  *(sv8*)(wb + (size_t)i * 8) = v;
}

// ---------------- Kernel 1: QKV projection ----------------
// 256 blocks x 1024 threads (16 waves). Block = 64 rows, 192 out cols.
// K-chunks of 128: per thread per chunk 3 W-glds + 2 x-loads + 1 ds_write.
__global__ __launch_bounds__(1024) void qkv_proj(
    const float* __restrict__ x,
    const short* __restrict__ wb,
    short* __restrict__ qw,
    short* __restrict__ kw,
    short* __restrict__ vtw)
{
  __shared__ short wlds[2][24576];  // 96 KB
  __shared__ short xlds[2][8192];   // 32 KB
  const int tid  = threadIdx.x;
  const int wid  = tid >> 6;
  const int lane = tid & 63;
  const int g    = lane >> 4;
  const int c16  = lane & 15;
  const int rowg = wid >> 2;
  const int ph   = wid & 3;
  const int row0 = blockIdx.x * 64;

  const int xr = tid >> 4, xs = tid & 15;
  const float* xsrc = x + (size_t)(row0 + xr) * CDIM + xs * 8;
  const int xwo = xr * 128 + ((xs ^ (xr & 7)) << 3);

  const int arow = rowg * 16 + c16;
  const int x7   = arow & 7;
  int rWo[3], rW7[3];
  #pragma unroll
  for (int p6 = 0; p6 < 3; ++p6) {
    int p = ph * 3 + p6;
    int r = (p >> 2) * 64 + (p & 3) * 16 + c16;
    rWo[p6] = r * 128;
    rW7[p6] = r & 7;
  }

  f32x4 acc[3];
  #pragma unroll
  for (int p6 = 0; p6 < 3; ++p6) acc[p6] = (f32x4){0.f, 0.f, 0.f, 0.f};

  float4 px[2][2];

  #pragma unroll
  for (int k2 = 0; k2 < 3; ++k2)
    glds16(wb + (size_t)(tid + k2 * 1024) * 8, &wlds[0][(tid + k2 * 1024) * 8]);
  px[0][0] = *(const float4*)(xsrc);
  px[0][1] = *(const float4*)(xsrc + 4);
  px[1][0] = *(const float4*)(xsrc + 128);
  px[1][1] = *(const float4*)(xsrc + 132);
  asm volatile("s_waitcnt vmcnt(2)" ::: "memory");
  {
    float4 A = px[0][0], B = px[0][1];
    sv8 v = {f2s(A.x), f2s(A.y), f2s(A.z), f2s(A.w),
             f2s(B.x), f2s(B.y), f2s(B.z), f2s(B.w)};
    *(sv8*)&xlds[0][xwo] = v;
  }
  asm volatile("s_waitcnt lgkmcnt(0)" ::: "memory");
  __builtin_amdgcn_sched_barrier(0);
  __builtin_amdgcn_s_barrier();

  #pragma unroll
  for (int t = 0; t < 8; ++t) {
    const int buf = t & 1;
    if (t < 7) {
      #pragma unroll
      for (int k2 = 0; k2 < 3; ++k2)
        glds16(wb + (size_t)((t + 1) * 3072 + tid + k2 * 1024) * 8,
               &wlds[buf ^ 1][(tid + k2 * 1024) * 8]);
    }
    if (t < 6) {
      px[t & 1][0] = *(const float4*)(xsrc + (t + 2) * 128);
      px[t & 1][1] = *(const float4*)(xsrc + (t + 2) * 128 + 4);
    }
    if (t < 7) {
      float4 A = px[(t + 1) & 1][0], B = px[(t + 1) & 1][1];
      sv8 v = {f2s(A.x), f2s(A.y), f2s(A.z), f2s(A.w),
               f2s(B.x), f2s(B.y), f2s(B.z), f2s(B.w)};
      *(sv8*)&xlds[buf ^ 1][xwo] = v;
    }
    #pragma unroll
    for (int kk = 0; kk < 4; ++kk) {
      int kslot = kk * 4 + g;
      sv8 a = *(const sv8*)&xlds[buf][arow * 128 + ((kslot ^ x7) << 3)];
      #pragma unroll
      for (int p6 = 0; p6 < 3; ++p6) {
        sv8 bfr = *(const sv8*)&wlds[buf][rWo[p6] + ((kslot ^ rW7[p6]) << 3)];
        acc[p6] = __builtin_amdgcn_mfma_f32_16x16x32_bf16(a, bfr, acc[p6], 0, 0, 0);
      }
    }
    if (t < 7) {
      if (t < 6) asm volatile("s_waitcnt vmcnt(2) lgkmcnt(0)" ::: "memory");
      else       asm volatile("s_waitcnt vmcnt(0) lgkmcnt(0)" ::: "memory");
      __builtin_amdgcn_sched_barrier(0);
      __builtin_amdgcn_s_barrier();
    }
  }

  #pragma unroll
  for (int p6 = 0; p6 < 3; ++p6) {
    int p = ph * 3 + p6, j = p >> 2, n = p & 3;
    int cc  = (n << 4) + c16;
    int rr0 = row0 + rowg * 16 + (g << 2);
    if (j == 2) {
      int b = rr0 >> 11, ti = rr0 & (TSEQ - 1);
      int kt = ti >> 6, key = ti & 63;
      sv4 v = {f2s(acc[p6][0]), f2s(acc[p6][1]), f2s(acc[p6][2]), f2s(acc[p6][3])};
      *(sv4*)&vtw[(((size_t)b * 32 + kt) * 64 + cc) * 64 +
                  ((((key >> 3) ^ (cc & 7)) << 3) | (key & 7))] = v;
    } else {
      #pragma unroll
      for (int r = 0; r < 4; ++r) {
        int rr = rr0 + r;
        if (j == 0) {
          qw[(size_t)rr * HD + cc] = f2s(acc[p6][r] * 0.03125f);
        } else {
          kw[(size_t)rr * HD + ((((cc >> 3) ^ (rr & 7)) << 3) | (cc & 7))] =
              f2s(acc[p6][r]);
        }
      }
    }
  }
}

// ---------------- Kernel 2: fused flash attention + combine ----------------
// 256 blocks x 512 threads. Block = (batch, qb). Waves 0-3 = key-half 0,
// waves 4-7 = key-half 1; per-half K/V dbuf; uniform barrier count.
// Full-width 4 KB/wave bridge: one fence + one PV cluster per tile.
__global__ __launch_bounds__(512) void attn(
    const short* __restrict__ qw,
    const short* __restrict__ kw,
    const short* __restrict__ vtw,
    float* __restrict__ out)
{
  __shared__ short kbuf[2][2][8192];   // [half][dbuf] 64 KB
  __shared__ short vbuf[2][2][8192];   // 64 KB
  __shared__ short bridge[8][2048];    // 32 KB (4 KB/wave) -> total 160 KB

  const int tid  = threadIdx.x;
  const int wid  = tid >> 6;
  const int h    = wid >> 2;
  const int lwid = wid & 3;
  const int ltid = tid & 255;
  const int lane = tid & 63;
  const int g    = lane >> 4;
  const int c16  = lane & 15;

  const int bid   = blockIdx.x;
  const int batch = bid & 7;
  const int qb    = bid >> 3;           // 0..31
  const int q0    = qb << 6;
  const size_t base = (size_t)batch * TSEQ * HD;

  const int ntot = (qb >> 1) + 1;       // 128-key tiles
  const int th_  = (ntot + 1) >> 1;
  const int t0   = h ? th_ : 0;
  const int cnt  = h ? (ntot - th_) : th_;

  const int qrow = q0 + (lwid << 4) + c16;
  sv8 qa0 = *(const sv8*)(qw + base + (size_t)qrow * HD + (g << 3));
  sv8 qa1 = *(const sv8*)(qw + base + (size_t)qrow * HD + 32 + (g << 3));

  float m = -1e30f, l = 0.f;
  f32x4 o[4];
  #pragma unroll
  for (int n = 0; n < 4; ++n) o[n] = (f32x4){0.f, 0.f, 0.f, 0.f};

  short* br = &bridge[wid][0];
  const int sx = c16 & 15;

  #define STAGE(tt, bb)                                                        \
    {                                                                          \
      const short* ksrc = kw + base + (size_t)(tt) * 8192;                     \
      const short* vsrc = vtw + ((size_t)batch * 32 + (tt) * 2) * 4096;        \
      _Pragma("unroll")                                                        \
      for (int q = 0; q < 4; ++q)                                              \
        glds16(ksrc + (ltid + q * 256) * 8, &kbuf[h][bb][(ltid + q * 256) * 8]);\
      _Pragma("unroll")                                                        \
      for (int q = 0; q < 4; ++q)                                              \
        glds16(vsrc + (ltid + q * 256) * 8, &vbuf[h][bb][(ltid + q * 256) * 8]);\
    }

  if (cnt > 0) STAGE(t0, 0);
  asm volatile("s_waitcnt vmcnt(0)" ::: "memory");
  __builtin_amdgcn_s_barrier();

  for (int it = 0; it < th_; ++it) {
    const int t   = t0 + it;
    const int buf = it & 1;
    const bool valid = it < cnt;
    if (valid && (it + 1 < cnt)) STAGE(t + 1, buf ^ 1);

    if (valid) {
      // ---- S^T = mfma(K, Q): D[row=key 0..127, col=q] ----
      f32x4 s[8];
      #pragma unroll
      for (int n = 0; n < 8; ++n) s[n] = (f32x4){0.f, 0.f, 0.f, 0.f};
      __builtin_amdgcn_s_setprio(1);
      #pragma unroll
      for (int n = 0; n < 8; ++n) {
        int kr = (n << 4) + c16;
        sv8 k0 = *(const sv8*)&kbuf[h][buf][kr * 64 + ((g ^ (kr & 7)) << 3)];
        s[n] = __builtin_amdgcn_mfma_f32_16x16x32_bf16(k0, qa0, s[n], 0, 0, 0);
        sv8 k1 = *(const sv8*)&kbuf[h][buf][kr * 64 + (((4 + g) ^ (kr & 7)) << 3)];
        s[n] = __builtin_amdgcn_mfma_f32_16x16x32_bf16(k1, qa1, s[n], 0, 0, 0);
      }
      __builtin_amdgcn_s_setprio(0);

      // ---- diagonal mask ----
      if (t == (qb >> 1)) {
        #pragma unroll
        for (int n = 0; n < 8; ++n) {
          int key = (t << 7) + (n << 4) + (g << 2);
          #pragma unroll
          for (int r = 0; r < 4; ++r)
            s[n][r] = (key + r <= qrow) ? s[n][r] : -1e30f;
        }
      }

      // ---- per-lane online softmax with defer-max (T13, THR=8) ----
      float pmax = -1e30f;
      #pragma unroll
      for (int n = 0; n < 8; ++n)
        pmax = fmaxf(pmax, fmaxf(fmaxf(s[n][0], s[n][1]), fmaxf(s[n][2], s[n][3])));
      float mnew  = m;
      float alpha = 1.f;
      const bool defer = (__all(pmax - m <= 8.0f) != 0);
      if (!defer) {
        float mx = fmaxf(pmax, __shfl_xor(pmax, 16));
        mx = fmaxf(mx, __shfl_xor(mx, 32));
        mnew  = fmaxf(m, mx);
        alpha = __expf(m - mnew);
        m = mnew;
      }

      // exp + full-width bridge write (128 keys, one pass)
      float sum = 0.f;
      #pragma unroll
      for (int n = 0; n < 8; ++n) {
        float p0 = __expf(s[n][0] - mnew);
        float p1 = __expf(s[n][1] - mnew);
        float p2 = __expf(s[n][2] - mnew);
        float p3 = __expf(s[n][3] - mnew);
        sum += (p0 + p1) + (p2 + p3);
        int slot = 2 * n + (g >> 1);
        uint2 w2; w2.x = pk2(p0, p1); w2.y = pk2(p2, p3);
        *(uint2*)&br[c16 * 128 + ((slot ^ sx) << 3) + ((g & 1) << 2)] = w2;
      }
      sum += __shfl_xor(sum, 16);
      sum += __shfl_xor(sum, 32);

      if (!defer) {
        l = l * alpha + sum;
        float af[4];
        #pragma unroll
        for (int r = 0; r < 4; ++r) af[r] = __shfl(alpha, (g << 2) + r);
        #pragma unroll
        for (int n = 0; n < 4; ++n)
          #pragma unroll
          for (int r = 0; r < 4; ++r) o[n][r] *= af[r];
      } else {
        l += sum;
      }

      // ---- single fence, single PV cluster (128 keys) ----
      asm volatile("s_waitcnt lgkmcnt(0)" ::: "memory");
      __builtin_amdgcn_sched_barrier(0);
      __builtin_amdgcn_s_setprio(1);
      #pragma unroll
      for (int kk = 0; kk < 4; ++kk) {
        int kslot = (kk << 2) + g;
        sv8 pa = *(const sv8*)&br[c16 * 128 + ((kslot ^ sx) << 3)];
        #pragma unroll
        for (int n = 0; n < 4; ++n) {
          int vr = (n << 4) + c16;
          sv8 vf = *(const sv8*)&vbuf[h][buf][(kslot >> 3) * 4096 + vr * 64 +
                                             (((kslot & 7) ^ (vr & 7)) << 3)];
          o[n] = __builtin_amdgcn_mfma_f32_16x16x32_bf16(pa, vf, o[n], 0, 0, 0);
        }
      }
      __builtin_amdgcn_s_setprio(0);
    }

    // uniform end-of-iteration drain + barrier (ALL waves, both halves)
    asm volatile("s_waitcnt vmcnt(0)" ::: "memory");
    __builtin_amdgcn_sched_barrier(0);
    __builtin_amdgcn_s_barrier();
  }

  // ---- in-LDS merge: h1 publishes (O,m,l); h0 merges and writes out ----
  float* OLDS = (float*)&kbuf[0][0][0];   // 4096 floats (16 KB)
  float* mlds = OLDS + 4096;              // 64 floats
  float* llds = mlds + 64;                // 64 floats

  if (h == 1) {
    #pragma unroll
    for (int n = 0; n < 4; ++n) {
      #pragma unroll
      for (int r = 0; r < 4; ++r) {
        int row = (lwid << 4) + (g << 2) + r;
        OLDS[row * 64 + (n << 4) + c16] = o[n][r];
      }
    }
    if (lane < 16) {
      mlds[(lwid << 4) + lane] = m;
      llds[(lwid << 4) + lane] = l;
    }
  }
  __syncthreads();
  if (h == 0) {
    #pragma unroll
    for (int r = 0; r < 4; ++r) {
      int row = (lwid << 4) + (g << 2) + r;
      float m0 = __shfl(m, (g << 2) + r);
      float l0 = __shfl(l, (g << 2) + r);
      float m1 = mlds[row], l1 = llds[row];
      float M  = fmaxf(m0, m1);
      float a0 = __expf(m0 - M), a1 = __expf(m1 - M);
      float invL = 1.f / (l0 * a0 + l1 * a1);
      #pragma unroll
      for (int n = 0; n < 4; ++n) {
        float v = (o[n][r] * a0 + OLDS[row * 64 + (n << 4) + c16] * a1) * invL;
        out[base + (size_t)(q0 + row) * HD + (n << 4) + c16] = v;
      }
    }
  }
  #undef STAGE
}

extern "C" void kernel_launch(void* const* d_in, const int* in_sizes, int n_in,
                              void* d_out, int out_size, void* d_ws, size_t ws_size,
                              hipStream_t stream) {
  const float* x  = (const float*)d_in[0];
  const float* Wk = (const float*)d_in[1];
  const float* Wq = (const float*)d_in[2];
  const float* Wv = (const float*)d_in[3];
  float* out = (float*)d_out;

  short* qw  = (short*)d_ws;                        // 2 MB
  short* kw  = qw + (size_t)MROWS * HD;             // 2 MB (row-swizzled)
  short* vtw = kw + (size_t)MROWS * HD;             // 2 MB (tiled+swizzled)
  short* wb  = vtw + (size_t)NB * HD * TSEQ;        // 384 KB (pre-swizzled)

  wcvt<<<dim3(96), dim3(256), 0, stream>>>(Wq, Wk, Wv, wb);
  qkv_proj<<<dim3(MROWS / 64), dim3(1024), 0, stream>>>(x, wb, qw, kw, vtw);
  attn<<<dim3(256), dim3(512), 0, stream>>>(qw, kw, vtw, out);
}